// Round 1
// baseline (976.126 us; speedup 1.0000x reference)
//
#include <hip/hip_runtime.h>

// KGAT 3-layer forward. Inputs (all f32/int32, setup_inputs order):
// 0 embed[N,64], 1 w1_0[64,64], 2 b1_0, 3 w2_0, 4 b2_0,
// 5 w1_1[32,64], 6 b1_1, 7 w2_1, 8 b2_1, 9 w1_2[16,32], 10 b1_2, 11 w2_2, 12 b2_2,
// 13 edge_val[E], 14 edge_row[E], 15 edge_col[E]
// Output f32 [N,176] = [embed | l2n(ego1) | l2n(ego2) | l2n(ego3)]

#define NODES 100000
#define OUT_STRIDE 176

static constexpr int SCAN_TILE = 1024;
static constexpr int NV = NODES + 1;                       // row_ptr entries
static constexpr int NBLK = (NV + SCAN_TILE - 1) / SCAN_TILE;  // 98

// ---------------- CSR build ----------------

__global__ void hist_kernel(const int* __restrict__ rows, int* __restrict__ counts, int e) {
    int i = blockIdx.x * blockDim.x + threadIdx.x;
    if (i < e) atomicAdd(&counts[rows[i]], 1);
}

__global__ __launch_bounds__(1024) void scan_reduce_kernel(const int* __restrict__ counts,
                                                           int* __restrict__ blockSums) {
    int i = blockIdx.x * SCAN_TILE + threadIdx.x;
    int v = (i < NODES) ? counts[i] : 0;
    #pragma unroll
    for (int off = 32; off; off >>= 1) v += __shfl_xor(v, off);
    __shared__ int ws[16];
    int lane = threadIdx.x & 63, wid = threadIdx.x >> 6;
    if (lane == 0) ws[wid] = v;
    __syncthreads();
    if (threadIdx.x == 0) {
        int t = 0;
        for (int k = 0; k < 16; ++k) t += ws[k];
        blockSums[blockIdx.x] = t;
    }
}

__global__ void scan_offsets_kernel(const int* __restrict__ blockSums, int* __restrict__ blockOffs) {
    __shared__ int s[NBLK];
    if (threadIdx.x < NBLK) s[threadIdx.x] = blockSums[threadIdx.x];
    __syncthreads();
    if (threadIdx.x == 0) {
        int run = 0;
        for (int b = 0; b < NBLK; ++b) { int t = s[b]; s[b] = run; run += t; }
    }
    __syncthreads();
    if (threadIdx.x < NBLK) blockOffs[threadIdx.x] = s[threadIdx.x];
}

__global__ __launch_bounds__(1024) void scan_write_kernel(const int* __restrict__ counts,
                                                          const int* __restrict__ blockOffs,
                                                          int* __restrict__ row_ptr,
                                                          int* __restrict__ cursor) {
    int i = blockIdx.x * SCAN_TILE + threadIdx.x;
    int lane = threadIdx.x & 63, wid = threadIdx.x >> 6;
    int v = (i < NODES) ? counts[i] : 0;
    int incl = v;
    #pragma unroll
    for (int off = 1; off < 64; off <<= 1) {
        int t = __shfl_up(incl, off);
        if (lane >= off) incl += t;
    }
    __shared__ int wsum[16];
    if (lane == 63) wsum[wid] = incl;
    __syncthreads();
    if (wid == 0) {
        int wv = (lane < 16) ? wsum[lane] : 0;
        int wincl = wv;
        #pragma unroll
        for (int off = 1; off < 16; off <<= 1) {
            int t = __shfl_up(wincl, off);
            if (lane >= off) wincl += t;
        }
        if (lane < 16) wsum[lane] = wincl - wv;  // exclusive wave offsets
    }
    __syncthreads();
    int excl = incl - v + wsum[wid] + blockOffs[blockIdx.x];
    if (i < NV) row_ptr[i] = excl;
    if (i < NODES) cursor[i] = excl;
}

__global__ void fill_kernel(const int* __restrict__ rows, const int* __restrict__ cols,
                            const float* __restrict__ vals, int* __restrict__ cursor,
                            uint2* __restrict__ se, int e) {
    int i = blockIdx.x * blockDim.x + threadIdx.x;
    if (i < e) {
        int pos = atomicAdd(&cursor[rows[i]], 1);
        se[pos] = make_uint2((unsigned)cols[i], __float_as_uint(vals[i]));
    }
}

// ---------------- output col 0..63 = raw embed ----------------

__global__ void copy_embed_kernel(const float* __restrict__ x, float* __restrict__ out) {
    int i = blockIdx.x * blockDim.x + threadIdx.x;
    if (i < NODES * 64) {
        int r = i >> 6, d = i & 63;
        out[(size_t)r * OUT_STRIDE + d] = x[i];
    }
}

// ---------------- fused layer: spmm + aggregate + l2norm ----------------
// One wave per row. lane d holds ego_d/side_d. Weights staged TRANSPOSED in
// LDS (w1t[d*DOUT+o]) so the aggregation read is lane-stride-1 (conflict-free)
// and the sum/bi read is a broadcast (free).

template <int DIN, int DOUT>
__global__ __launch_bounds__(256) void layer_kernel(
    const float* __restrict__ x, const uint2* __restrict__ edges,
    const int* __restrict__ row_ptr,
    const float* __restrict__ w1, const float* __restrict__ b1,
    const float* __restrict__ w2, const float* __restrict__ b2,
    float* __restrict__ ego_out,   // [N, DOUT] un-normalized (null for last layer)
    float* __restrict__ outp,      // d_out + column offset, row stride 176
    int n) {
    __shared__ float w1t[DIN * DOUT], w2t[DIN * DOUT];
    __shared__ float b1s[DOUT], b2s[DOUT];
    __shared__ float sumb[4][DIN], bib[4][DIN];

    for (int idx = threadIdx.x; idx < DIN * DOUT; idx += 256) {
        int o = idx / DIN, d = idx % DIN;   // w is [DOUT][DIN] row-major
        w1t[d * DOUT + o] = w1[idx];
        w2t[d * DOUT + o] = w2[idx];
    }
    for (int idx = threadIdx.x; idx < DOUT; idx += 256) { b1s[idx] = b1[idx]; b2s[idx] = b2[idx]; }
    __syncthreads();

    int wid = threadIdx.x >> 6, lane = threadIdx.x & 63;
    for (int r = blockIdx.x * 4 + wid; r < n; r += gridDim.x * 4) {
        float ego = (lane < DIN) ? x[(size_t)r * DIN + lane] : 0.f;
        float side = 0.f;
        int s = row_ptr[r], e = row_ptr[r + 1];
        for (int j = s; j < e; ++j) {
            uint2 ed = edges[j];                       // uniform across wave
            float v = __uint_as_float(ed.y);
            if (lane < DIN) side += v * x[(size_t)ed.x * DIN + lane];
        }
        if (lane < DIN) {
            sumb[wid][lane] = ego + side;              // wave-private LDS slot,
            bib[wid][lane]  = ego * side;              // no barrier needed
        }
        float o_val = 0.f;
        if (lane < DOUT) {
            float a1 = b1s[lane], a2 = b2s[lane];
            #pragma unroll
            for (int d = 0; d < DIN; ++d) {
                a1 += sumb[wid][d] * w1t[d * DOUT + lane];
                a2 += bib[wid][d]  * w2t[d * DOUT + lane];
            }
            a1 = a1 > 0.f ? a1 : 0.01f * a1;
            a2 = a2 > 0.f ? a2 : 0.01f * a2;
            o_val = a1 + a2;
        }
        float sq = o_val * o_val;
        #pragma unroll
        for (int off = 32; off; off >>= 1) sq += __shfl_xor(sq, off);
        float inv = 1.f / fmaxf(sqrtf(sq), 1e-12f);
        if (lane < DOUT) {
            if (ego_out) ego_out[(size_t)r * DOUT + lane] = o_val;
            outp[(size_t)r * OUT_STRIDE + lane] = o_val * inv;
        }
    }
}

// ---------------- launch ----------------

static size_t align_up(size_t x) { return (x + 255) & ~(size_t)255; }

extern "C" void kernel_launch(void* const* d_in, const int* in_sizes, int n_in,
                              void* d_out, int out_size, void* d_ws, size_t ws_size,
                              hipStream_t stream) {
    const float* embed = (const float*)d_in[0];
    const float* w1_0 = (const float*)d_in[1];  const float* b1_0 = (const float*)d_in[2];
    const float* w2_0 = (const float*)d_in[3];  const float* b2_0 = (const float*)d_in[4];
    const float* w1_1 = (const float*)d_in[5];  const float* b1_1 = (const float*)d_in[6];
    const float* w2_1 = (const float*)d_in[7];  const float* b2_1 = (const float*)d_in[8];
    const float* w1_2 = (const float*)d_in[9];  const float* b1_2 = (const float*)d_in[10];
    const float* w2_2 = (const float*)d_in[11]; const float* b2_2 = (const float*)d_in[12];
    const float* edge_val = (const float*)d_in[13];
    const int*   edge_row = (const int*)d_in[14];
    const int*   edge_col = (const int*)d_in[15];
    const int E = in_sizes[14];
    const int N = in_sizes[0] / 64;
    float* out = (float*)d_out;

    // workspace carve-up (~49.3 MB)
    char* ws = (char*)d_ws;
    size_t off = 0;
    int* counts    = (int*)(ws + off); off = align_up(off + (size_t)N * 4);
    int* row_ptr   = (int*)(ws + off); off = align_up(off + (size_t)(N + 1) * 4);
    int* cursor    = (int*)(ws + off); off = align_up(off + (size_t)N * 4);
    int* blockSums = (int*)(ws + off); off = align_up(off + (size_t)NBLK * 4);
    int* blockOffs = (int*)(ws + off); off = align_up(off + (size_t)NBLK * 4);
    uint2* sorted  = (uint2*)(ws + off); off = align_up(off + (size_t)E * 8);
    float* ego1    = (float*)(ws + off); off = align_up(off + (size_t)N * 64 * 4);
    float* ego2    = (float*)(ws + off); off = align_up(off + (size_t)N * 32 * 4);
    (void)ws_size; (void)n_in; (void)out_size;

    hipMemsetAsync(counts, 0, (size_t)N * 4, stream);

    int eg = (E + 255) / 256;
    hist_kernel<<<eg, 256, 0, stream>>>(edge_row, counts, E);
    scan_reduce_kernel<<<NBLK, 1024, 0, stream>>>(counts, blockSums);
    scan_offsets_kernel<<<1, 128, 0, stream>>>(blockSums, blockOffs);
    scan_write_kernel<<<NBLK, 1024, 0, stream>>>(counts, blockOffs, row_ptr, cursor);
    fill_kernel<<<eg, 256, 0, stream>>>(edge_row, edge_col, edge_val, cursor, sorted, E);

    copy_embed_kernel<<<(N * 64 + 255) / 256, 256, 0, stream>>>(embed, out);

    layer_kernel<64, 64><<<2048, 256, 0, stream>>>(embed, sorted, row_ptr,
        w1_0, b1_0, w2_0, b2_0, ego1, out + 64, N);
    layer_kernel<64, 32><<<2048, 256, 0, stream>>>(ego1, sorted, row_ptr,
        w1_1, b1_1, w2_1, b2_1, ego2, out + 128, N);
    layer_kernel<32, 16><<<2048, 256, 0, stream>>>(ego2, sorted, row_ptr,
        w1_2, b1_2, w2_2, b2_2, nullptr, out + 160, N);
}

// Round 2
// 352.859 us; speedup vs baseline: 2.7663x; 2.7663x over previous
//
#include <hip/hip_runtime.h>

// KGAT 3-layer forward. Inputs (all f32/int32, setup_inputs order):
// 0 embed[N,64], 1 w1_0[64,64], 2 b1_0, 3 w2_0, 4 b2_0,
// 5 w1_1[32,64], 6 b1_1, 7 w2_1, 8 b2_1, 9 w1_2[16,32], 10 b1_2, 11 w2_2, 12 b2_2,
// 13 edge_val[E], 14 edge_row[E], 15 edge_col[E]
// Output f32 [N,176] = [embed | l2n(ego1) | l2n(ego2) | l2n(ego3)]

#define NODES 100000
#define OUT_STRIDE 176

static constexpr int SCAN_TILE = 1024;
static constexpr int NV = NODES + 1;
static constexpr int NBLK = (NV + SCAN_TILE - 1) / SCAN_TILE;  // 98

// ---------------- CSR build ----------------

__global__ void hist_kernel(const int* __restrict__ rows, int* __restrict__ counts, int e) {
    int i = blockIdx.x * blockDim.x + threadIdx.x;
    if (i < e) atomicAdd(&counts[rows[i]], 1);
}

__global__ __launch_bounds__(1024) void scan_reduce_kernel(const int* __restrict__ counts,
                                                           int* __restrict__ blockSums) {
    int i = blockIdx.x * SCAN_TILE + threadIdx.x;
    int v = (i < NODES) ? counts[i] : 0;
    #pragma unroll
    for (int off = 32; off; off >>= 1) v += __shfl_xor(v, off);
    __shared__ int ws[16];
    int lane = threadIdx.x & 63, wid = threadIdx.x >> 6;
    if (lane == 0) ws[wid] = v;
    __syncthreads();
    if (threadIdx.x == 0) {
        int t = 0;
        for (int k = 0; k < 16; ++k) t += ws[k];
        blockSums[blockIdx.x] = t;
    }
}

__global__ void scan_offsets_kernel(const int* __restrict__ blockSums, int* __restrict__ blockOffs) {
    __shared__ int s[NBLK];
    if (threadIdx.x < NBLK) s[threadIdx.x] = blockSums[threadIdx.x];
    __syncthreads();
    if (threadIdx.x == 0) {
        int run = 0;
        for (int b = 0; b < NBLK; ++b) { int t = s[b]; s[b] = run; run += t; }
    }
    __syncthreads();
    if (threadIdx.x < NBLK) blockOffs[threadIdx.x] = s[threadIdx.x];
}

__global__ __launch_bounds__(1024) void scan_write_kernel(const int* __restrict__ counts,
                                                          const int* __restrict__ blockOffs,
                                                          int* __restrict__ row_ptr,
                                                          int* __restrict__ cursor) {
    int i = blockIdx.x * SCAN_TILE + threadIdx.x;
    int lane = threadIdx.x & 63, wid = threadIdx.x >> 6;
    int v = (i < NODES) ? counts[i] : 0;
    int incl = v;
    #pragma unroll
    for (int off = 1; off < 64; off <<= 1) {
        int t = __shfl_up(incl, off);
        if (lane >= off) incl += t;
    }
    __shared__ int wsum[16];
    if (lane == 63) wsum[wid] = incl;
    __syncthreads();
    if (wid == 0) {
        int wv = (lane < 16) ? wsum[lane] : 0;
        int wincl = wv;
        #pragma unroll
        for (int off = 1; off < 16; off <<= 1) {
            int t = __shfl_up(wincl, off);
            if (lane >= off) wincl += t;
        }
        if (lane < 16) wsum[lane] = wincl - wv;  // exclusive wave offsets
    }
    __syncthreads();
    int excl = incl - v + wsum[wid] + blockOffs[blockIdx.x];
    if (i < NV) row_ptr[i] = excl;
    if (i < NODES) cursor[i] = excl;
}

__global__ void fill_kernel(const int* __restrict__ rows, const int* __restrict__ cols,
                            const float* __restrict__ vals, int* __restrict__ cursor,
                            uint2* __restrict__ se, int e) {
    int i = blockIdx.x * blockDim.x + threadIdx.x;
    if (i < e) {
        int pos = atomicAdd(&cursor[rows[i]], 1);
        se[pos] = make_uint2((unsigned)cols[i], __float_as_uint(vals[i]));
    }
}

// ---------------- output col 0..63 = raw embed (float4) ----------------

__global__ void copy_embed_kernel(const float4* __restrict__ x4, float4* __restrict__ out4) {
    int i = blockIdx.x * blockDim.x + threadIdx.x;
    if (i < NODES * 16) {
        int r = i >> 4, c = i & 15;
        out4[r * (OUT_STRIDE / 4) + c] = x4[i];   // cols 0..63
    }
}

// ---------------- fused layer: spmm + aggregate + l2norm ----------------
// float4 per lane: LPR = DIN/4 lanes per row, RPW = 64/LPR rows per wave.
// Edge loop unrolled x4 -> up to 4*RPW gathers in flight per wave.
// Aggregation: weights transposed in LDS (contiguous per-lane reads),
// sum/bi rows padded +4 floats so the RPW row-groups broadcast from
// distinct banks.

template <int DIN, int DOUT>
__global__ __launch_bounds__(256, 4) void layer_kernel(
    const float* __restrict__ x, const uint2* __restrict__ edges,
    const int* __restrict__ row_ptr,
    const float* __restrict__ w1, const float* __restrict__ b1,
    const float* __restrict__ w2, const float* __restrict__ b2,
    float* __restrict__ ego_out,   // [N, DOUT] un-normalized (null for last layer)
    float* __restrict__ outp,      // d_out + column offset, row stride 176
    int n) {
    constexpr int LPR = DIN / 4;        // lanes per row
    constexpr int RPW = 64 / LPR;       // rows per wave
    constexpr int RPB = 4 * RPW;        // rows per block
    constexpr int OPL = DOUT / LPR;     // outputs per lane
    constexpr int PAD = 4;

    __shared__ float w1t[DIN * DOUT], w2t[DIN * DOUT];  // [d][o]
    __shared__ float b1s[DOUT], b2s[DOUT];
    __shared__ float sum_lds[4][RPW][DIN + PAD];
    __shared__ float bi_lds[4][RPW][DIN + PAD];

    for (int idx = threadIdx.x; idx < DIN * DOUT; idx += 256) {
        int o = idx / DIN, d = idx % DIN;   // w is [DOUT][DIN] row-major
        w1t[d * DOUT + o] = w1[idx];
        w2t[d * DOUT + o] = w2[idx];
    }
    for (int idx = threadIdx.x; idx < DOUT; idx += 256) { b1s[idx] = b1[idx]; b2s[idx] = b2[idx]; }
    __syncthreads();

    const float4* __restrict__ x4 = (const float4*)x;
    int wid = threadIdx.x >> 6, lane = threadIdx.x & 63;
    int g = lane / LPR;     // row-group within wave
    int li = lane % LPR;    // float4 chunk within row

    for (int base = blockIdx.x * RPB; base < n; base += gridDim.x * RPB) {
        int r = base + wid * RPW + g;
        bool valid = r < n;
        int rr = valid ? r : 0;
        int s = valid ? row_ptr[rr] : 0;
        int e = valid ? row_ptr[rr + 1] : 0;

        float4 ego = x4[(size_t)rr * LPR + li];  // issue early
        float4 side = make_float4(0.f, 0.f, 0.f, 0.f);

        int j = s;
        for (; j + 3 < e; j += 4) {
            uint2 e0 = edges[j], e1 = edges[j + 1], e2 = edges[j + 2], e3 = edges[j + 3];
            float4 x0 = x4[(size_t)e0.x * LPR + li];
            float4 x1 = x4[(size_t)e1.x * LPR + li];
            float4 x2 = x4[(size_t)e2.x * LPR + li];
            float4 x3 = x4[(size_t)e3.x * LPR + li];
            float v0 = __uint_as_float(e0.y), v1 = __uint_as_float(e1.y);
            float v2 = __uint_as_float(e2.y), v3 = __uint_as_float(e3.y);
            side.x += v0 * x0.x + v1 * x1.x + v2 * x2.x + v3 * x3.x;
            side.y += v0 * x0.y + v1 * x1.y + v2 * x2.y + v3 * x3.y;
            side.z += v0 * x0.z + v1 * x1.z + v2 * x2.z + v3 * x3.z;
            side.w += v0 * x0.w + v1 * x1.w + v2 * x2.w + v3 * x3.w;
        }
        for (; j < e; ++j) {
            uint2 ed = edges[j];
            float v = __uint_as_float(ed.y);
            float4 xv = x4[(size_t)ed.x * LPR + li];
            side.x += v * xv.x; side.y += v * xv.y;
            side.z += v * xv.z; side.w += v * xv.w;
        }

        // stage sum/bi (wave-private slots, no barrier needed)
        float4 sm = make_float4(ego.x + side.x, ego.y + side.y, ego.z + side.z, ego.w + side.w);
        float4 bi = make_float4(ego.x * side.x, ego.y * side.y, ego.z * side.z, ego.w * side.w);
        *(float4*)&sum_lds[wid][g][li * 4] = sm;
        *(float4*)&bi_lds[wid][g][li * 4] = bi;

        // aggregation: lane computes outs o0..o0+OPL-1 of row (wid,g)
        int o0 = li * OPL;
        float a1[OPL], a2[OPL];
        #pragma unroll
        for (int k = 0; k < OPL; ++k) { a1[k] = b1s[o0 + k]; a2[k] = b2s[o0 + k]; }
        #pragma unroll 4
        for (int d = 0; d < DIN; ++d) {
            float sv = sum_lds[wid][g][d];
            float tv = bi_lds[wid][g][d];
            #pragma unroll
            for (int k = 0; k < OPL; ++k) {
                a1[k] += sv * w1t[d * DOUT + o0 + k];
                a2[k] += tv * w2t[d * DOUT + o0 + k];
            }
        }
        float ov[OPL];
        float sq = 0.f;
        #pragma unroll
        for (int k = 0; k < OPL; ++k) {
            float u1 = a1[k] > 0.f ? a1[k] : 0.01f * a1[k];
            float u2 = a2[k] > 0.f ? a2[k] : 0.01f * a2[k];
            ov[k] = u1 + u2;
            sq += ov[k] * ov[k];
        }
        #pragma unroll
        for (int off = 1; off < LPR; off <<= 1) sq += __shfl_xor(sq, off);
        float inv = 1.f / fmaxf(sqrtf(sq), 1e-12f);

        if (valid) {
            #pragma unroll
            for (int k = 0; k < OPL; ++k) {
                if (ego_out) ego_out[(size_t)r * DOUT + o0 + k] = ov[k];
                outp[(size_t)r * OUT_STRIDE + o0 + k] = ov[k] * inv;
            }
        }
    }
}

// ---------------- launch ----------------

static size_t align_up(size_t x) { return (x + 255) & ~(size_t)255; }

extern "C" void kernel_launch(void* const* d_in, const int* in_sizes, int n_in,
                              void* d_out, int out_size, void* d_ws, size_t ws_size,
                              hipStream_t stream) {
    const float* embed = (const float*)d_in[0];
    const float* w1_0 = (const float*)d_in[1];  const float* b1_0 = (const float*)d_in[2];
    const float* w2_0 = (const float*)d_in[3];  const float* b2_0 = (const float*)d_in[4];
    const float* w1_1 = (const float*)d_in[5];  const float* b1_1 = (const float*)d_in[6];
    const float* w2_1 = (const float*)d_in[7];  const float* b2_1 = (const float*)d_in[8];
    const float* w1_2 = (const float*)d_in[9];  const float* b1_2 = (const float*)d_in[10];
    const float* w2_2 = (const float*)d_in[11]; const float* b2_2 = (const float*)d_in[12];
    const float* edge_val = (const float*)d_in[13];
    const int*   edge_row = (const int*)d_in[14];
    const int*   edge_col = (const int*)d_in[15];
    const int E = in_sizes[14];
    const int N = in_sizes[0] / 64;
    float* out = (float*)d_out;

    // workspace carve-up (~49.3 MB)
    char* ws = (char*)d_ws;
    size_t off = 0;
    int* counts    = (int*)(ws + off); off = align_up(off + (size_t)N * 4);
    int* row_ptr   = (int*)(ws + off); off = align_up(off + (size_t)(N + 1) * 4);
    int* cursor    = (int*)(ws + off); off = align_up(off + (size_t)N * 4);
    int* blockSums = (int*)(ws + off); off = align_up(off + (size_t)NBLK * 4);
    int* blockOffs = (int*)(ws + off); off = align_up(off + (size_t)NBLK * 4);
    uint2* sorted  = (uint2*)(ws + off); off = align_up(off + (size_t)E * 8);
    float* ego1    = (float*)(ws + off); off = align_up(off + (size_t)N * 64 * 4);
    float* ego2    = (float*)(ws + off); off = align_up(off + (size_t)N * 32 * 4);
    (void)ws_size; (void)n_in; (void)out_size;

    hipMemsetAsync(counts, 0, (size_t)N * 4, stream);

    int eg = (E + 255) / 256;
    hist_kernel<<<eg, 256, 0, stream>>>(edge_row, counts, E);
    scan_reduce_kernel<<<NBLK, 1024, 0, stream>>>(counts, blockSums);
    scan_offsets_kernel<<<1, 128, 0, stream>>>(blockSums, blockOffs);
    scan_write_kernel<<<NBLK, 1024, 0, stream>>>(counts, blockOffs, row_ptr, cursor);
    fill_kernel<<<eg, 256, 0, stream>>>(edge_row, edge_col, edge_val, cursor, sorted, E);

    copy_embed_kernel<<<(N * 16 + 255) / 256, 256, 0, stream>>>(
        (const float4*)embed, (float4*)out);

    layer_kernel<64, 64><<<2048, 256, 0, stream>>>(embed, sorted, row_ptr,
        w1_0, b1_0, w2_0, b2_0, ego1, out + 64, N);
    layer_kernel<64, 32><<<2048, 256, 0, stream>>>(ego1, sorted, row_ptr,
        w1_1, b1_1, w2_1, b2_1, ego2, out + 128, N);
    layer_kernel<32, 16><<<2048, 256, 0, stream>>>(ego2, sorted, row_ptr,
        w1_2, b1_2, w2_2, b2_2, nullptr, out + 160, N);
}

// Round 3
// 242.838 us; speedup vs baseline: 4.0197x; 1.4531x over previous
//
#include <hip/hip_runtime.h>

// KGAT 3-layer forward. Inputs (all f32/int32, setup_inputs order):
// 0 embed[N,64], 1 w1_0[64,64], 2 b1_0, 3 w2_0, 4 b2_0,
// 5 w1_1[32,64], 6 b1_1, 7 w2_1, 8 b2_1, 9 w1_2[16,32], 10 b1_2, 11 w2_2, 12 b2_2,
// 13 edge_val[E], 14 edge_row[E], 15 edge_col[E]
// Output f32 [N,176] = [embed | l2n(ego1) | l2n(ego2) | l2n(ego3)]

#define NODES 100000
#define OUT_STRIDE 176

typedef _Float16 half2_t __attribute__((ext_vector_type(2)));
typedef _Float16 half4_t __attribute__((ext_vector_type(4)));

static constexpr int SCAN_TILE = 1024;
static constexpr int NV = NODES + 1;
static constexpr int NBLK = (NV + SCAN_TILE - 1) / SCAN_TILE;  // 98

// ---------------- CSR build ----------------

__global__ void hist_kernel(const int* __restrict__ rows, int* __restrict__ counts,
                            int* __restrict__ rank, int e) {
    int i = blockIdx.x * blockDim.x + threadIdx.x;
    if (i < e) rank[i] = atomicAdd(&counts[rows[i]], 1);
}

__global__ __launch_bounds__(1024) void scan_reduce_kernel(const int* __restrict__ counts,
                                                           int* __restrict__ blockSums) {
    int i = blockIdx.x * SCAN_TILE + threadIdx.x;
    int v = (i < NODES) ? counts[i] : 0;
    #pragma unroll
    for (int off = 32; off; off >>= 1) v += __shfl_xor(v, off);
    __shared__ int ws[16];
    int lane = threadIdx.x & 63, wid = threadIdx.x >> 6;
    if (lane == 0) ws[wid] = v;
    __syncthreads();
    if (threadIdx.x == 0) {
        int t = 0;
        for (int k = 0; k < 16; ++k) t += ws[k];
        blockSums[blockIdx.x] = t;
    }
}

__global__ void scan_offsets_kernel(const int* __restrict__ blockSums, int* __restrict__ blockOffs) {
    __shared__ int s[NBLK];
    if (threadIdx.x < NBLK) s[threadIdx.x] = blockSums[threadIdx.x];
    __syncthreads();
    if (threadIdx.x == 0) {
        int run = 0;
        for (int b = 0; b < NBLK; ++b) { int t = s[b]; s[b] = run; run += t; }
    }
    __syncthreads();
    if (threadIdx.x < NBLK) blockOffs[threadIdx.x] = s[threadIdx.x];
}

__global__ __launch_bounds__(1024) void scan_write_kernel(const int* __restrict__ counts,
                                                          const int* __restrict__ blockOffs,
                                                          int* __restrict__ row_ptr) {
    int i = blockIdx.x * SCAN_TILE + threadIdx.x;
    int lane = threadIdx.x & 63, wid = threadIdx.x >> 6;
    int v = (i < NODES) ? counts[i] : 0;
    int incl = v;
    #pragma unroll
    for (int off = 1; off < 64; off <<= 1) {
        int t = __shfl_up(incl, off);
        if (lane >= off) incl += t;
    }
    __shared__ int wsum[16];
    if (lane == 63) wsum[wid] = incl;
    __syncthreads();
    if (wid == 0) {
        int wv = (lane < 16) ? wsum[lane] : 0;
        int wincl = wv;
        #pragma unroll
        for (int off = 1; off < 16; off <<= 1) {
            int t = __shfl_up(wincl, off);
            if (lane >= off) wincl += t;
        }
        if (lane < 16) wsum[lane] = wincl - wv;  // exclusive wave offsets
    }
    __syncthreads();
    int excl = incl - v + wsum[wid] + blockOffs[blockIdx.x];
    if (i < NV) row_ptr[i] = excl;
}

__global__ void fill_kernel(const int* __restrict__ rows, const int* __restrict__ cols,
                            const float* __restrict__ vals, const int* __restrict__ row_ptr,
                            const int* __restrict__ rank, uint2* __restrict__ se, int e) {
    int i = blockIdx.x * blockDim.x + threadIdx.x;
    if (i < e) {
        int pos = row_ptr[rows[i]] + rank[i];
        se[pos] = make_uint2((unsigned)cols[i], __float_as_uint(vals[i]));
    }
}

// ------- cols 0..63 = raw embed (f32) + build fp16 copy of embed -------

__global__ void prep_embed_kernel(const float4* __restrict__ x4, float4* __restrict__ out4,
                                  half4_t* __restrict__ xh) {
    int i = blockIdx.x * blockDim.x + threadIdx.x;
    if (i < NODES * 16) {
        int r = i >> 4, c = i & 15;
        float4 v = x4[i];
        out4[r * (OUT_STRIDE / 4) + c] = v;
        xh[i] = half4_t{(_Float16)v.x, (_Float16)v.y, (_Float16)v.z, (_Float16)v.w};
    }
}

// ---------------- fused layer: spmm + aggregate + l2norm ----------------
// x is fp16 [n, DIN]. LPR = DIN/4 lanes per row (half4/lane), RPW = 64/LPR
// rows per wave. Weights/sum/bi staged fp16 in LDS; aggregation via
// v_dot2_f32_f16 (f32 accumulate). Output f32 slice + fp16 ego for next layer.

template <int DIN, int DOUT>
__global__ __launch_bounds__(256, 6) void layer_kernel(
    const half4_t* __restrict__ xh, const uint2* __restrict__ edges,
    const int* __restrict__ row_ptr,
    const float* __restrict__ w1, const float* __restrict__ b1,
    const float* __restrict__ w2, const float* __restrict__ b2,
    half4_t* __restrict__ ego_out,  // [n, DOUT/4] fp16 (null for last layer)
    float* __restrict__ outp,       // d_out + column offset, row stride 176
    int n) {
    constexpr int LPR = DIN / 4;        // lanes per row
    constexpr int RPW = 64 / LPR;       // rows per wave
    constexpr int RPB = 4 * RPW;        // rows per block
    constexpr int OPL = DOUT / LPR;     // outputs per lane
    constexpr int PADH = 4;             // halves; keeps groups on distinct banks, 8B align
    constexpr int SROW = DIN + PADH;

    __shared__ half2_t w1h[(DIN / 2) * DOUT], w2h[(DIN / 2) * DOUT];  // [d2][o]
    __shared__ _Float16 sum_h[4][RPW][SROW], bi_h[4][RPW][SROW];

    // destination-contiguous staging: conflict-free LDS writes
    for (int idx = threadIdx.x; idx < (DIN / 2) * DOUT; idx += 256) {
        int d2 = idx / DOUT, o = idx % DOUT;      // w is [DOUT][DIN] row-major
        w1h[idx] = half2_t{(_Float16)w1[o * DIN + 2 * d2], (_Float16)w1[o * DIN + 2 * d2 + 1]};
        w2h[idx] = half2_t{(_Float16)w2[o * DIN + 2 * d2], (_Float16)w2[o * DIN + 2 * d2 + 1]};
    }
    __syncthreads();

    int wid = threadIdx.x >> 6, lane = threadIdx.x & 63;
    int g = lane / LPR;     // row-group within wave
    int li = lane % LPR;    // half4 chunk within row
    int o0 = li * OPL;

    float bb1[OPL], bb2[OPL];
    #pragma unroll
    for (int k = 0; k < OPL; ++k) { bb1[k] = b1[o0 + k]; bb2[k] = b2[o0 + k]; }

    for (int base = blockIdx.x * RPB; base < n; base += gridDim.x * RPB) {
        int r = base + wid * RPW + g;
        bool valid = r < n;
        int rr = valid ? r : 0;
        int s = valid ? row_ptr[rr] : 0;
        int e = valid ? row_ptr[rr + 1] : 0;

        half4_t egoh = xh[(size_t)rr * LPR + li];  // issue early
        float4 side = make_float4(0.f, 0.f, 0.f, 0.f);

        int j = s;
        for (; j + 3 < e; j += 4) {
            uint2 e0 = edges[j], e1 = edges[j + 1], e2 = edges[j + 2], e3 = edges[j + 3];
            half4_t x0 = xh[(size_t)e0.x * LPR + li];
            half4_t x1 = xh[(size_t)e1.x * LPR + li];
            half4_t x2 = xh[(size_t)e2.x * LPR + li];
            half4_t x3 = xh[(size_t)e3.x * LPR + li];
            float v0 = __uint_as_float(e0.y), v1 = __uint_as_float(e1.y);
            float v2 = __uint_as_float(e2.y), v3 = __uint_as_float(e3.y);
            side.x += v0 * (float)x0.x + v1 * (float)x1.x + v2 * (float)x2.x + v3 * (float)x3.x;
            side.y += v0 * (float)x0.y + v1 * (float)x1.y + v2 * (float)x2.y + v3 * (float)x3.y;
            side.z += v0 * (float)x0.z + v1 * (float)x1.z + v2 * (float)x2.z + v3 * (float)x3.z;
            side.w += v0 * (float)x0.w + v1 * (float)x1.w + v2 * (float)x2.w + v3 * (float)x3.w;
        }
        for (; j < e; ++j) {
            uint2 ed = edges[j];
            float v = __uint_as_float(ed.y);
            half4_t xv = xh[(size_t)ed.x * LPR + li];
            side.x += v * (float)xv.x; side.y += v * (float)xv.y;
            side.z += v * (float)xv.z; side.w += v * (float)xv.w;
        }

        float ex = (float)egoh.x, ey = (float)egoh.y, ez = (float)egoh.z, ew = (float)egoh.w;
        half4_t sm4 = half4_t{(_Float16)(ex + side.x), (_Float16)(ey + side.y),
                              (_Float16)(ez + side.z), (_Float16)(ew + side.w)};
        half4_t bi4 = half4_t{(_Float16)(ex * side.x), (_Float16)(ey * side.y),
                              (_Float16)(ez * side.z), (_Float16)(ew * side.w)};
        *(half4_t*)&sum_h[wid][g][li * 4] = sm4;   // wave-private, no barrier
        *(half4_t*)&bi_h[wid][g][li * 4] = bi4;

        float a1[OPL], a2[OPL];
        #pragma unroll
        for (int k = 0; k < OPL; ++k) { a1[k] = bb1[k]; a2[k] = bb2[k]; }
        #pragma unroll 8
        for (int d2 = 0; d2 < DIN / 2; ++d2) {
            half2_t sv = *(const half2_t*)&sum_h[wid][g][2 * d2];
            half2_t tv = *(const half2_t*)&bi_h[wid][g][2 * d2];
            #pragma unroll
            for (int k = 0; k < OPL; ++k) {
                half2_t wa = w1h[d2 * DOUT + o0 + k];
                half2_t wb = w2h[d2 * DOUT + o0 + k];
#if __has_builtin(__builtin_amdgcn_fdot2)
                a1[k] = __builtin_amdgcn_fdot2(sv, wa, a1[k], false);
                a2[k] = __builtin_amdgcn_fdot2(tv, wb, a2[k], false);
#else
                a1[k] = fmaf((float)sv.x, (float)wa.x, fmaf((float)sv.y, (float)wa.y, a1[k]));
                a2[k] = fmaf((float)tv.x, (float)wb.x, fmaf((float)tv.y, (float)wb.y, a2[k]));
#endif
            }
        }
        float ov[OPL];
        float sq = 0.f;
        #pragma unroll
        for (int k = 0; k < OPL; ++k) {
            float u1 = a1[k] > 0.f ? a1[k] : 0.01f * a1[k];
            float u2 = a2[k] > 0.f ? a2[k] : 0.01f * a2[k];
            ov[k] = u1 + u2;
            sq += ov[k] * ov[k];
        }
        #pragma unroll
        for (int off = 1; off < LPR; off <<= 1) sq += __shfl_xor(sq, off);
        float inv = 1.f / fmaxf(sqrtf(sq), 1e-12f);

        if (valid) {
            if (ego_out) {
                half4_t oh;
                #pragma unroll
                for (int k = 0; k < OPL; ++k) oh[k] = (_Float16)ov[k];
                // OPL==4 -> half4 store; OPL==2 -> half2 store
                if constexpr (OPL == 4) {
                    *(half4_t*)&ego_out[((size_t)r * DOUT + o0) / 4] = oh;
                } else {
                    half2_t o2 = {oh[0], oh[1]};
                    *((half2_t*)ego_out + ((size_t)r * DOUT + o0) / 2) = o2;
                }
            }
            #pragma unroll
            for (int k = 0; k < OPL; ++k)
                outp[(size_t)r * OUT_STRIDE + o0 + k] = ov[k] * inv;
        }
    }
}

// ---------------- launch ----------------

static size_t align_up(size_t x) { return (x + 255) & ~(size_t)255; }

extern "C" void kernel_launch(void* const* d_in, const int* in_sizes, int n_in,
                              void* d_out, int out_size, void* d_ws, size_t ws_size,
                              hipStream_t stream) {
    const float* embed = (const float*)d_in[0];
    const float* w1_0 = (const float*)d_in[1];  const float* b1_0 = (const float*)d_in[2];
    const float* w2_0 = (const float*)d_in[3];  const float* b2_0 = (const float*)d_in[4];
    const float* w1_1 = (const float*)d_in[5];  const float* b1_1 = (const float*)d_in[6];
    const float* w2_1 = (const float*)d_in[7];  const float* b2_1 = (const float*)d_in[8];
    const float* w1_2 = (const float*)d_in[9];  const float* b1_2 = (const float*)d_in[10];
    const float* w2_2 = (const float*)d_in[11]; const float* b2_2 = (const float*)d_in[12];
    const float* edge_val = (const float*)d_in[13];
    const int*   edge_row = (const int*)d_in[14];
    const int*   edge_col = (const int*)d_in[15];
    const int E = in_sizes[14];
    const int N = in_sizes[0] / 64;
    float* out = (float*)d_out;

    // workspace carve-up (~47 MB)
    char* ws = (char*)d_ws;
    size_t off = 0;
    int* counts    = (int*)(ws + off); off = align_up(off + (size_t)N * 4);
    int* row_ptr   = (int*)(ws + off); off = align_up(off + (size_t)(N + 1) * 4);
    int* rank      = (int*)(ws + off); off = align_up(off + (size_t)E * 4);
    int* blockSums = (int*)(ws + off); off = align_up(off + (size_t)NBLK * 4);
    int* blockOffs = (int*)(ws + off); off = align_up(off + (size_t)NBLK * 4);
    uint2* sorted  = (uint2*)(ws + off); off = align_up(off + (size_t)E * 8);
    half4_t* embed_h = (half4_t*)(ws + off); off = align_up(off + (size_t)N * 64 * 2);
    half4_t* ego1_h  = (half4_t*)(ws + off); off = align_up(off + (size_t)N * 64 * 2);
    half4_t* ego2_h  = (half4_t*)(ws + off); off = align_up(off + (size_t)N * 32 * 2);
    (void)ws_size; (void)n_in; (void)out_size;

    hipMemsetAsync(counts, 0, (size_t)N * 4, stream);

    int eg = (E + 255) / 256;
    hist_kernel<<<eg, 256, 0, stream>>>(edge_row, counts, rank, E);
    scan_reduce_kernel<<<NBLK, 1024, 0, stream>>>(counts, blockSums);
    scan_offsets_kernel<<<1, 128, 0, stream>>>(blockSums, blockOffs);
    scan_write_kernel<<<NBLK, 1024, 0, stream>>>(counts, blockOffs, row_ptr);
    fill_kernel<<<eg, 256, 0, stream>>>(edge_row, edge_col, edge_val, row_ptr, rank, sorted, E);

    prep_embed_kernel<<<(N * 16 + 255) / 256, 256, 0, stream>>>(
        (const float4*)embed, (float4*)out, embed_h);

    layer_kernel<64, 64><<<2048, 256, 0, stream>>>(embed_h, sorted, row_ptr,
        w1_0, b1_0, w2_0, b2_0, ego1_h, out + 64, N);
    layer_kernel<64, 32><<<2048, 256, 0, stream>>>(ego1_h, sorted, row_ptr,
        w1_1, b1_1, w2_1, b2_1, ego2_h, out + 128, N);
    layer_kernel<32, 16><<<2048, 256, 0, stream>>>(ego2_h, sorted, row_ptr,
        w1_2, b1_2, w2_2, b2_2, nullptr, out + 160, N);
}